// Round 3
// baseline (1572.989 us; speedup 1.0000x reference)
//
#include <hip/hip_runtime.h>
#include <hip/hip_bf16.h>

#define TT 1024
#define BB 512

typedef _Float16 half_t;
typedef __attribute__((ext_vector_type(8))) _Float16 v8h;
typedef __attribute__((ext_vector_type(4))) float v4f;

// Single-instruction v_rcp_f32 — avoids the IEEE div sequence.
__device__ __forceinline__ float sigf(float x) {
    return __builtin_amdgcn_rcpf(1.0f + __expf(-x));
}
__device__ __forceinline__ float tanhfast(float x) {
    return fmaf(2.0f, __builtin_amdgcn_rcpf(1.0f + __expf(-2.0f * x)), -1.0f);
}

// Drain ONLY lgkmcnt (LDS) at the barrier — global prefetch stays in flight.
__device__ __forceinline__ void barrier_lds_only() {
    asm volatile("s_waitcnt lgkmcnt(0)\n\ts_barrier" ::: "memory");
}

// LSTM scan — R8: producer/consumer wave specialization.
//
// Post-mortem of R6/R7: a wave issues in order; an MFMA that cannot enter the
// busy matrix pipe blocks ALL later issue from that wave. So within one wave,
// MFMA pipe time (24 x ~19 = 466 cyc), VALU (~300) and exposed latencies
// (LDS ~120, nonlin ~100, barrier ~50) ADD -> the measured ~1134 cyc wall.
// Intra-wave reordering (R6 gx-first, R7 sched_barrier) cannot fix this.
//
// Fix: move the recurrence-independent work to a DIFFERENT wave on the same
// SIMD. 512 threads/block = 8 waves = 2/SIMD:
//   waves 0-3 (consumer, setprio(1) hot section): per step, 3 LDS reads
//     (h x2, gx x1), 8 h-MFMAs, nonlinearity, h write. Short issue stream ->
//     wall ~= latency chain + 155 cyc MFMA.
//   waves 4-7 (producer): x global loads (depth-2 lead) + 16 gx MFMAs with
//     bias folded into the C-seed; writes gx(t+2) into a 4-slot LDS ring,
//     lane-linear 16B per lane (conflict-free b128).
// Ring: consumer reads slot t%4 at step t; producer writes slot (t+2)%4 ->
// always >=1 barrier between write and read, never same slot in one step.
// One lgkm-only barrier per step, as before. h double-buffered in LDS.
template<int R, bool IN_F32, bool W16, bool WRITE_SEQ, bool WRITE_LAST>
__global__ __launch_bounds__(512, 2)
void lstm_scan(const void* __restrict__ in_v, const half_t* __restrict__ w16,
               const float* __restrict__ w_ih, const float* __restrict__ w_hh,
               const float* __restrict__ b_ih, const float* __restrict__ b_hh,
               int layer, int use_grid_dir,
               half_t* __restrict__ out_seq, float* __restrict__ out_last)
{
    const int dir = use_grid_dir ? blockIdx.y : 0;
    const int wrow = layer * 2 + dir;
    const int col_off = dir * 64;
    const int b0 = blockIdx.x * R;
    const int tid = threadIdx.x;
    const int wid = tid >> 6;          // 0..7
    const bool prod = wid >= 4;        // waves 4-7: gx producers
    const int wv = wid & 3;            // column group (j range), shared by the pair
    const int l  = tid & 63;
    const int q  = l >> 4;
    const int n16 = l & 15;
    const int j = wv * 16 + n16;
    const int rowc = ((n16 >> 2) < R) ? (n16 >> 2) : (R - 1);  // A-row -> batch row

    __shared__ __align__(16) half_t hs[2][16][72];     // 4.5 KiB, h double buffer
    __shared__ __align__(16) float  gxr[4][4][64][4];  // 16 KiB gx ring [slot][wv][lane][gate]

    {   // zero hs: 2*16*72 halves = 288 v8h
        if (tid < 288) {
            v8h z;
            #pragma unroll
            for (int e = 0; e < 8; ++e) z[e] = (half_t)0.f;
            ((v8h*)hs)[tid] = z;
        }
    }

    // Weight fragments: B[k][n16] = W[gt*64+j][k], k = kt*32+q*8+e.
    // Producer holds x-weights (K=128 -> 4 frags/gate) + bias seed;
    // consumer holds h-weights (K=64 -> 2 frags/gate).
    v8h wbx[4][4];
    v4f bseed[4];
    v8h wbh[4][2];
    if (prod) {
        #pragma unroll
        for (int gt = 0; gt < 4; ++gt) {
            const int grow = wrow * 256 + gt * 64 + j;
            if constexpr (W16) {
                const half_t* p = w16 + (size_t)grow * 192 + q * 8;
                #pragma unroll
                for (int kt = 0; kt < 4; ++kt) wbx[gt][kt] = *(const v8h*)(p + kt * 32);
            } else {
                const float* pih = w_ih + (size_t)grow * 128 + q * 8;
                #pragma unroll
                for (int kt = 0; kt < 4; ++kt) {
                    const float4 a = *(const float4*)(pih + kt * 32);
                    const float4 b = *(const float4*)(pih + kt * 32 + 4);
                    v8h f;
                    f[0] = (half_t)a.x; f[1] = (half_t)a.y; f[2] = (half_t)a.z; f[3] = (half_t)a.w;
                    f[4] = (half_t)b.x; f[5] = (half_t)b.y; f[6] = (half_t)b.z; f[7] = (half_t)b.w;
                    wbx[gt][kt] = f;
                }
            }
            const float bs = b_ih[grow] + b_hh[grow];
            bseed[gt] = (v4f){bs, bs, bs, bs};
        }
    } else {
        #pragma unroll
        for (int gt = 0; gt < 4; ++gt) {
            const int grow = wrow * 256 + gt * 64 + j;
            if constexpr (W16) {
                const half_t* p = w16 + (size_t)grow * 192 + 128 + q * 8;
                #pragma unroll
                for (int kt = 0; kt < 2; ++kt) wbh[gt][kt] = *(const v8h*)(p + kt * 32);
            } else {
                const float* phh = w_hh + (size_t)grow * 64 + q * 8;
                #pragma unroll
                for (int kt = 0; kt < 2; ++kt) {
                    const float4 a = *(const float4*)(phh + kt * 32);
                    const float4 b = *(const float4*)(phh + kt * 32 + 4);
                    v8h f;
                    f[0] = (half_t)a.x; f[1] = (half_t)a.y; f[2] = (half_t)a.z; f[3] = (half_t)a.w;
                    f[4] = (half_t)b.x; f[5] = (half_t)b.y; f[6] = (half_t)b.z; f[7] = (half_t)b.w;
                    wbh[gt][kt] = f;
                }
            }
        }
    }

    const long t0 = dir ? (TT - 1) : 0;
    const long xstep = dir ? -128 : 128;

    const float*  xp32 = nullptr;
    const half_t* xp16 = nullptr;
    if constexpr (IN_F32) xp32 = (const float*)in_v + ((size_t)(b0 + rowc) * TT + t0) * 128 + q * 8;
    else                  xp16 = (const half_t*)in_v + ((size_t)(b0 + rowc) * TT + t0) * 128 + q * 8;

    half_t* op = nullptr;
    if constexpr (WRITE_SEQ) {
        const int qr = (q < R) ? q : (R - 1);
        op = out_seq + ((size_t)(b0 + qr) * TT + t0) * 128 + col_off + j;
    }

    auto load_x = [&](v8h* dst) {
        if constexpr (IN_F32) {
            #pragma unroll
            for (int kt = 0; kt < 4; ++kt) {
                const float4 a = *(const float4*)(xp32 + kt * 32);
                const float4 b = *(const float4*)(xp32 + kt * 32 + 4);
                v8h f;
                f[0] = (half_t)a.x; f[1] = (half_t)a.y; f[2] = (half_t)a.z; f[3] = (half_t)a.w;
                f[4] = (half_t)b.x; f[5] = (half_t)b.y; f[6] = (half_t)b.z; f[7] = (half_t)b.w;
                dst[kt] = f;
            }
        } else {
            #pragma unroll
            for (int kt = 0; kt < 4; ++kt) dst[kt] = *(const v8h*)(xp16 + kt * 32);
        }
    };
    auto adv_x = [&]() { if constexpr (IN_F32) xp32 += xstep; else xp16 += xstep; };

    // Producer: gx(t) = x(t).W_ih + bias for 4 gates -> ring slot (conflict-free b128).
    auto gxstore = [&](const v8h (&xf)[4], int slot) {
        v4f g;
        #pragma unroll
        for (int gt = 0; gt < 4; ++gt) {
            v4f a = __builtin_amdgcn_mfma_f32_16x16x32_f16(xf[0], wbx[gt][0], bseed[gt], 0, 0, 0);
            a = __builtin_amdgcn_mfma_f32_16x16x32_f16(xf[1], wbx[gt][1], a, 0, 0, 0);
            a = __builtin_amdgcn_mfma_f32_16x16x32_f16(xf[2], wbx[gt][2], a, 0, 0, 0);
            a = __builtin_amdgcn_mfma_f32_16x16x32_f16(xf[3], wbx[gt][3], a, 0, 0, 0);
            g[gt] = a[0];
        }
        *(v4f*)&gxr[slot][wv][l][0] = g;
    };

    float c = 0.f, hcur = 0.f;
    const v4f z4 = {0.f, 0.f, 0.f, 0.f};

    // Consumer: one recurrence step. Short issue stream; setprio(1) so the
    // SIMD scheduler favors it over the co-resident producer wave.
    auto cstep = [&](int p, int pb) {
        __builtin_amdgcn_s_setprio(1);
        const v8h hf0 = *(const v8h*)&hs[pb][n16][q * 8];
        const v8h hf1 = *(const v8h*)&hs[pb][n16][32 + q * 8];
        const v4f gxl = *(const v4f*)&gxr[p][wv][l][0];
        v4f acc[4];
        #pragma unroll
        for (int gt = 0; gt < 4; ++gt)
            acc[gt] = __builtin_amdgcn_mfma_f32_16x16x32_f16(hf0, wbh[gt][0], z4, 0, 0, 0);
        #pragma unroll
        for (int gt = 0; gt < 4; ++gt)
            acc[gt] = __builtin_amdgcn_mfma_f32_16x16x32_f16(hf1, wbh[gt][1], acc[gt], 0, 0, 0);
        const float iv = sigf(acc[0][0] + gxl[0]);
        const float fv = sigf(acc[1][0] + gxl[1]);
        const float gv = tanhfast(acc[2][0] + gxl[2]);
        const float ov = sigf(acc[3][0] + gxl[3]);
        c = fv * c + iv * gv;
        const float h = ov * tanhfast(c);
        __builtin_amdgcn_s_setprio(0);
        if (q < R) {
            const half_t h16 = (half_t)h;
            hs[pb ^ 1][4 * q][j] = h16;
            if constexpr (WRITE_SEQ) { *op = h16; op += xstep; }
            hcur = h;
        }
    };

    // Producer x-prefetch: 4 rotating buffers, load-use distance 2 steps.
    v8h x0[4], x1[4], x2[4], x3[4];
    if (prod) {
        load_x(x0); adv_x();
        load_x(x1); adv_x();
        load_x(x2); adv_x();
        load_x(x3); adv_x();
        gxstore(x0, 0);     // gx(0)
        gxstore(x1, 1);     // gx(1)
    }
    barrier_lds_only();     // hs zero-init + ring slots 0,1 visible

    for (int tt = 0; tt < TT; tt += 4) {
        // t = tt+0: consumer reads slot0/pb0; producer loads x(t+4), writes gx(t+2)->slot2
        if (prod) {
            if (tt + 4 < TT) { load_x(x0); adv_x(); }
            if (tt + 2 < TT) gxstore(x2, 2);
        } else {
            cstep(0, 0);
        }
        barrier_lds_only();
        // t = tt+1
        if (prod) {
            if (tt + 5 < TT) { load_x(x1); adv_x(); }
            if (tt + 3 < TT) gxstore(x3, 3);
        } else {
            cstep(1, 1);
        }
        barrier_lds_only();
        // t = tt+2
        if (prod) {
            if (tt + 6 < TT) { load_x(x2); adv_x(); }
            if (tt + 4 < TT) gxstore(x0, 0);
        } else {
            cstep(2, 0);
        }
        barrier_lds_only();
        // t = tt+3
        if (prod) {
            if (tt + 7 < TT) { load_x(x3); adv_x(); }
            if (tt + 5 < TT) gxstore(x1, 1);
        } else {
            cstep(3, 1);
        }
        barrier_lds_only();
    }

    if constexpr (WRITE_LAST) {
        if (!prod && q < R) out_last[(size_t)(b0 + q) * 64 + j] = hcur;
    }
}

// ---------------- weight fp32 -> packed fp16 rows of 192 ----------------
__global__ __launch_bounds__(256)
void cvt_w(const float* __restrict__ w_ih, const float* __restrict__ w_hh,
           half_t* __restrict__ w16)
{
    const int id = blockIdx.x * 256 + threadIdx.x;  // 1024 rows * 192
    const int row = id / 192, k = id % 192;
    const float v = (k < 128) ? w_ih[row * 128 + k] : w_hh[row * 64 + (k - 128)];
    w16[id] = (half_t)v;
}

// ---------------- x fp32 -> fp16 ----------------
__global__ __launch_bounds__(256)
void cvt_x(const float* __restrict__ in, half_t* __restrict__ out)
{
    const size_t i = ((size_t)blockIdx.x * 256 + threadIdx.x) * 8;
    const float4 a = *(const float4*)(in + i);
    const float4 b = *(const float4*)(in + i + 4);
    v8h f;
    f[0] = (half_t)a.x; f[1] = (half_t)a.y; f[2] = (half_t)a.z; f[3] = (half_t)a.w;
    f[4] = (half_t)b.x; f[5] = (half_t)b.y; f[6] = (half_t)b.z; f[7] = (half_t)b.w;
    *(v8h*)(out + i) = f;
}

// ---------------- Layer 2 backward (single step, h0=0) + FC ----------------
__global__ __launch_bounds__(256)
void l2bwd_fc(const half_t* __restrict__ in, const float* __restrict__ w_ih,
              const float* __restrict__ b_ih, const float* __restrict__ b_hh,
              const float* __restrict__ hlast, const float* __restrict__ fc_w,
              const float* __restrict__ fc_b, float* __restrict__ out)
{
    const int b = blockIdx.x;
    const int g = threadIdx.x;
    __shared__ float gpre[256];
    __shared__ float hb[64];

    float acc = b_ih[3 * 256 + g] + b_hh[3 * 256 + g];
    const float* wp = w_ih + ((size_t)(3 * 256 + g)) * 128;
    const half_t* xp = in + ((size_t)b * TT + (TT - 1)) * 128;
    #pragma unroll
    for (int k = 0; k < 128; k += 8) {
        const float4 w0 = *(const float4*)(wp + k);
        const float4 w1 = *(const float4*)(wp + k + 4);
        const v8h xv = *(const v8h*)(xp + k);
        acc = fmaf(w0.x, (float)xv[0], acc); acc = fmaf(w0.y, (float)xv[1], acc);
        acc = fmaf(w0.z, (float)xv[2], acc); acc = fmaf(w0.w, (float)xv[3], acc);
        acc = fmaf(w1.x, (float)xv[4], acc); acc = fmaf(w1.y, (float)xv[5], acc);
        acc = fmaf(w1.z, (float)xv[6], acc); acc = fmaf(w1.w, (float)xv[7], acc);
    }
    gpre[g] = acc;
    __syncthreads();

    if (g < 64) {
        const float i  = sigf(gpre[g]);
        const float gg = tanhfast(gpre[128 + g]);
        const float o  = sigf(gpre[192 + g]);
        hb[g] = o * tanhfast(i * gg);
    }
    __syncthreads();

    if (g < 64) {
        float p = fc_w[g] * hlast[(size_t)b * 64 + g] + fc_w[64 + g] * hb[g];
        #pragma unroll
        for (int off = 32; off > 0; off >>= 1) p += __shfl_down(p, off);
        if (g == 0) out[b] = p + fc_b[0];
    }
}

extern "C" void kernel_launch(void* const* d_in, const int* in_sizes, int n_in,
                              void* d_out, int out_size, void* d_ws, size_t ws_size,
                              hipStream_t stream)
{
    const float* x    = (const float*)d_in[0];
    const float* w_ih = (const float*)d_in[1];
    const float* w_hh = (const float*)d_in[2];
    const float* b_ih = (const float*)d_in[3];
    const float* b_hh = (const float*)d_in[4];
    const float* fc_w = (const float*)d_in[5];
    const float* fc_b = (const float*)d_in[6];
    float* out = (float*)d_out;

    const size_t seq_b   = (size_t)BB * TT * 128 * sizeof(half_t);  // 128 MiB
    const size_t w16_b   = (size_t)1024 * 192 * sizeof(half_t);     // 384 KiB
    const size_t hlast_b = (size_t)BB * 64 * sizeof(float);         // 128 KiB

    if (ws_size >= w16_b + hlast_b + 2 * seq_b) {
        half_t* w16   = (half_t*)d_ws;
        float*  hlast = (float*)((char*)d_ws + w16_b);
        half_t* x16   = (half_t*)((char*)d_ws + w16_b + hlast_b);
        half_t* out1  = (half_t*)((char*)d_ws + w16_b + hlast_b + seq_b);

        cvt_w<<<768, 256, 0, stream>>>(w_ih, w_hh, w16);
        cvt_x<<<(BB * TT * 128 / 8) / 256, 256, 0, stream>>>(x, x16);
        lstm_scan<4, false, true, true, false><<<dim3(BB / 4, 2), 512, 0, stream>>>(
            x16, w16, w_ih, w_hh, b_ih, b_hh, 0, 1, out1, nullptr);
        lstm_scan<4, false, true, false, true><<<dim3(BB / 4, 1), 512, 0, stream>>>(
            out1, w16, w_ih, w_hh, b_ih, b_hh, 1, 0, nullptr, hlast);
        l2bwd_fc<<<BB, 256, 0, stream>>>(out1, w_ih, b_ih, b_hh, hlast, fc_w, fc_b, out);
    } else if (ws_size >= 2 * seq_b + hlast_b) {
        half_t* x16   = (half_t*)d_ws;
        half_t* out1  = (half_t*)((char*)d_ws + seq_b);
        float*  hlast = (float*)((char*)d_ws + 2 * seq_b);

        cvt_x<<<(BB * TT * 128 / 8) / 256, 256, 0, stream>>>(x, x16);
        lstm_scan<4, false, false, true, false><<<dim3(BB / 4, 2), 512, 0, stream>>>(
            x16, nullptr, w_ih, w_hh, b_ih, b_hh, 0, 1, out1, nullptr);
        lstm_scan<4, false, false, false, true><<<dim3(BB / 4, 1), 512, 0, stream>>>(
            out1, nullptr, w_ih, w_hh, b_ih, b_hh, 1, 0, nullptr, hlast);
        l2bwd_fc<<<BB, 256, 0, stream>>>(out1, w_ih, b_ih, b_hh, hlast, fc_w, fc_b, out);
    } else {
        half_t* out1  = (half_t*)d_ws;
        float*  hlast = (float*)((char*)d_ws + seq_b);

        lstm_scan<4, true, false, true, false><<<dim3(BB / 4, 2), 512, 0, stream>>>(
            x, nullptr, w_ih, w_hh, b_ih, b_hh, 0, 1, out1, nullptr);
        lstm_scan<4, false, false, false, true><<<dim3(BB / 4, 1), 512, 0, stream>>>(
            out1, nullptr, w_ih, w_hh, b_ih, b_hh, 1, 0, nullptr, hlast);
        l2bwd_fc<<<BB, 256, 0, stream>>>(out1, w_ih, b_ih, b_hh, hlast, fc_w, fc_b, out);
    }
}

// Round 4
// 1015.662 us; speedup vs baseline: 1.5487x; 1.5487x over previous
//
#include <hip/hip_runtime.h>
#include <hip/hip_bf16.h>

#define TT 1024
#define BB 512

typedef _Float16 half_t;
typedef __attribute__((ext_vector_type(8))) _Float16 v8h;
typedef __attribute__((ext_vector_type(4))) float v4f;

// Single-instruction v_rcp_f32 — avoids the IEEE div sequence.
__device__ __forceinline__ float sigf(float x) {
    return __builtin_amdgcn_rcpf(1.0f + __expf(-x));
}
__device__ __forceinline__ float tanhfast(float x) {
    return fmaf(2.0f, __builtin_amdgcn_rcpf(1.0f + __expf(-2.0f * x)), -1.0f);
}

// Drain ONLY lgkmcnt (LDS) at the barrier — global prefetch stays in flight.
__device__ __forceinline__ void barrier_lds_only() {
    asm volatile("s_waitcnt lgkmcnt(0)\n\ts_barrier" ::: "memory");
}

// LSTM scan — R9: time-batched gx through the wasted MFMA M-dimension.
//
// Post-mortem R8: wave specialization regressed (645 us) with UNCHANGED
// absolute MFMA cycles -> MFMA issue occupancy is shared per SIMD no matter
// which wave supplies it; producer/consumer waves cannot overlap MFMA with
// MFMA. The per-step wall is per-SIMD issue work: 24 MFMA x ~19 + ~330 VALU
// + latency remnants ~= 1100 cyc. So: REDUCE ISSUE WORK.
//
// Only 4 of 16 MFMA A-rows carried data (batch rows at m=4r). gx = x.W_ih is
// recurrence-independent -> pack 4 TIMESTEPS x 4 batch rows into the 16
// A-rows: A[m] = x(t4 + (m>>2), row m&3). One 16-MFMA set computes gx for a
// whole 4-step group => 4 gx MFMAs/step instead of 16. Per step: 8 h-MFMAs +
// 4 gx-MFMAs (one gate's K-chain per phase). C[m=(4s+r)] results are
// transposed through an LDS ring:
//   write (phase s = gate s): lane(q,n16) ds_write_b128 v4f(rows 0..3) at
//         ring[buf][wv][step=q][gate=s][n16][0..3]   (structural-min banks)
//   read  (phase s): 4x ds_read_b32 ring[buf][wv][s][gt][n16][row=q] (2-way)
// x loads drop 4x: 4 per group (burst at group start, consumed next group =
// 4-phase lead >> HBM latency). The per-phase gx chain is register-only and
// issues UNDER the h-fragment LDS latency. Same 4-wave / 256-thread /
// 1-barrier-per-step skeleton as the 468 us best. Bias folded into the gx
// MFMA C-seed. Tail x-loads clamp t4 to TT-4 (garbage gx never consumed).
template<int R, bool IN_F32, bool W16, bool WRITE_SEQ, bool WRITE_LAST>
__global__ __launch_bounds__(256, 1)
void lstm_scan(const void* __restrict__ in_v, const half_t* __restrict__ w16,
               const float* __restrict__ w_ih, const float* __restrict__ w_hh,
               const float* __restrict__ b_ih, const float* __restrict__ b_hh,
               int layer, int use_grid_dir,
               half_t* __restrict__ out_seq, float* __restrict__ out_last)
{
    const int dir = use_grid_dir ? blockIdx.y : 0;
    const int wrow = layer * 2 + dir;
    const int col_off = dir * 64;
    const int b0 = blockIdx.x * R;
    const int tid = threadIdx.x;
    const int wv = tid >> 6;
    const int l  = tid & 63;
    const int q  = l >> 4;
    const int n16 = l & 15;
    const int j = wv * 16 + n16;
    const int arow = n16 & 3;   // A-row -> batch row   (requires R==4)
    const int as4  = n16 >> 2;  // A-row -> step offset within group

    __shared__ __align__(16) half_t hs[2][16][72];            // h double buffer
    __shared__ __align__(16) float ring[2][4][4][4][16][4];   // [buf][wv][step][gate][n16][row]

    {   // zero hs: 2*16*72 halves = 288 v8h
        v8h z;
        #pragma unroll
        for (int e = 0; e < 8; ++e) z[e] = (half_t)0.f;
        ((v8h*)hs)[tid] = z;
        if (tid < 32) ((v8h*)hs)[256 + tid] = z;
    }

    // Weight fragments: B[k][n16] = W[gt*64+j][k], k = kt*32+q*8+e.
    v8h wbx[4][4];   // x-weights (K=128)
    v8h wbh[4][2];   // h-weights (K=64)
    v4f bseed[4];    // bias broadcast into all C rows of the gx MFMA
    #pragma unroll
    for (int gt = 0; gt < 4; ++gt) {
        const int grow = wrow * 256 + gt * 64 + j;
        if constexpr (W16) {
            const half_t* p = w16 + (size_t)grow * 192 + q * 8;
            #pragma unroll
            for (int kt = 0; kt < 4; ++kt) wbx[gt][kt] = *(const v8h*)(p + kt * 32);
            #pragma unroll
            for (int kt = 0; kt < 2; ++kt) wbh[gt][kt] = *(const v8h*)(p + 128 + kt * 32);
        } else {
            const float* pih = w_ih + (size_t)grow * 128 + q * 8;
            #pragma unroll
            for (int kt = 0; kt < 4; ++kt) {
                const float4 a = *(const float4*)(pih + kt * 32);
                const float4 b = *(const float4*)(pih + kt * 32 + 4);
                v8h f;
                f[0] = (half_t)a.x; f[1] = (half_t)a.y; f[2] = (half_t)a.z; f[3] = (half_t)a.w;
                f[4] = (half_t)b.x; f[5] = (half_t)b.y; f[6] = (half_t)b.z; f[7] = (half_t)b.w;
                wbx[gt][kt] = f;
            }
            const float* phh = w_hh + (size_t)grow * 64 + q * 8;
            #pragma unroll
            for (int kt = 0; kt < 2; ++kt) {
                const float4 a = *(const float4*)(phh + kt * 32);
                const float4 b = *(const float4*)(phh + kt * 32 + 4);
                v8h f;
                f[0] = (half_t)a.x; f[1] = (half_t)a.y; f[2] = (half_t)a.z; f[3] = (half_t)a.w;
                f[4] = (half_t)b.x; f[5] = (half_t)b.y; f[6] = (half_t)b.z; f[7] = (half_t)b.w;
                wbh[gt][kt] = f;
            }
        }
        const float bs = b_ih[grow] + b_hh[grow];
        bseed[gt] = (v4f){bs, bs, bs, bs};
    }

    const long t0 = dir ? (TT - 1) : 0;
    const long xstep = dir ? -128 : 128;

    half_t* op = nullptr;
    if constexpr (WRITE_SEQ) {
        op = out_seq + ((size_t)(b0 + q) * TT + t0) * 128 + col_off + j;
    }

    // Per-group x base pointer: lane (q,n16) loads row (b0+arow), scan-step
    // t4+as4 (time-mapped by dir), halves [kt*32+q*8 .. +7].
    const half_t* gld16 = nullptr;
    const float*  gld32 = nullptr;
    auto set_gld = [&](int t4) {
        int t4c = (t4 > TT - 4) ? (TT - 4) : t4;  // tail clamp: garbage gx, never read
        const int tt = dir ? (TT - 1 - (t4c + as4)) : (t4c + as4);
        const size_t off = ((size_t)(b0 + arow) * TT + tt) * 128 + q * 8;
        if constexpr (IN_F32) gld32 = (const float*)in_v + off;
        else                  gld16 = (const half_t*)in_v + off;
    };
    auto ldfrag = [&](int kt) -> v8h {
        if constexpr (IN_F32) {
            const float4 a = *(const float4*)(gld32 + kt * 32);
            const float4 b = *(const float4*)(gld32 + kt * 32 + 4);
            v8h f;
            f[0] = (half_t)a.x; f[1] = (half_t)a.y; f[2] = (half_t)a.z; f[3] = (half_t)a.w;
            f[4] = (half_t)b.x; f[5] = (half_t)b.y; f[6] = (half_t)b.z; f[7] = (half_t)b.w;
            return f;
        } else {
            return *(const v8h*)(gld16 + kt * 32);
        }
    };

    // One gate's gx K-chain over a 4-step group (bias-seeded).
    auto gx_gate = [&](const v8h (&xf)[4], int gt) -> v4f {
        v4f a = __builtin_amdgcn_mfma_f32_16x16x32_f16(xf[0], wbx[gt][0], bseed[gt], 0, 0, 0);
        a = __builtin_amdgcn_mfma_f32_16x16x32_f16(xf[1], wbx[gt][1], a, 0, 0, 0);
        a = __builtin_amdgcn_mfma_f32_16x16x32_f16(xf[2], wbx[gt][2], a, 0, 0, 0);
        a = __builtin_amdgcn_mfma_f32_16x16x32_f16(xf[3], wbx[gt][3], a, 0, 0, 0);
        return a;
    };

    float c = 0.f, hcur = 0.f;
    const v4f z4 = {0.f, 0.f, 0.f, 0.f};

    // 4 phases of group g: read ring[bufR], write gx(group g+1) into ring[bufR^1].
    // xc holds x(group g+1); xn receives x(group g+2) via a group-start burst.
    auto run_group = [&](int bufR, const v8h (&xc)[4], v8h (&xn)[4]) {
        const int bufW = bufR ^ 1;
        // group-start load burst (consumed next group -> 4-phase lead)
        xn[0] = ldfrag(0); xn[1] = ldfrag(1); xn[2] = ldfrag(2); xn[3] = ldfrag(3);
        #pragma unroll
        for (int s = 0; s < 4; ++s) {
            const int pb = s & 1;
            const v8h hf0 = *(const v8h*)&hs[pb][n16][q * 8];
            const v8h hf1 = *(const v8h*)&hs[pb][n16][32 + q * 8];
            const float g0 = ring[bufR][wv][s][0][n16][q];
            const float g1 = ring[bufR][wv][s][1][n16][q];
            const float g2 = ring[bufR][wv][s][2][n16][q];
            const float g3 = ring[bufR][wv][s][3][n16][q];
            // gate-s gx chain for NEXT group: register-only, issues under the
            // hf/ring LDS latency.
            const v4f gg = gx_gate(xc, s);
            v4f acc[4];
            #pragma unroll
            for (int gt = 0; gt < 4; ++gt)
                acc[gt] = __builtin_amdgcn_mfma_f32_16x16x32_f16(hf0, wbh[gt][0], z4, 0, 0, 0);
            #pragma unroll
            for (int gt = 0; gt < 4; ++gt)
                acc[gt] = __builtin_amdgcn_mfma_f32_16x16x32_f16(hf1, wbh[gt][1], acc[gt], 0, 0, 0);
            const float iv = sigf(acc[0][0] + g0);
            const float fv = sigf(acc[1][0] + g1);
            const float gv = tanhfast(acc[2][0] + g2);
            const float ov = sigf(acc[3][0] + g3);
            c = fv * c + iv * gv;
            const float h = ov * tanhfast(c);
            // gate-s results -> ring (v4f = rows 0..3 of step q, 16B-aligned)
            *(v4f*)&ring[bufW][wv][q][s][n16][0] = gg;
            const half_t h16 = (half_t)h;
            hs[pb ^ 1][4 * q][j] = h16;
            if constexpr (WRITE_SEQ) { *op = h16; op += xstep; }
            hcur = h;
            barrier_lds_only();
        }
    };

    // Prologue: ring[0] <- gx(group 0); xA <- x(group 1).
    v8h xt[4], xA[4], xB[4];
    set_gld(0);
    xt[0] = ldfrag(0); xt[1] = ldfrag(1); xt[2] = ldfrag(2); xt[3] = ldfrag(3);
    set_gld(4);
    xA[0] = ldfrag(0); xA[1] = ldfrag(1); xA[2] = ldfrag(2); xA[3] = ldfrag(3);
    #pragma unroll
    for (int gt = 0; gt < 4; ++gt) {
        const v4f g0 = gx_gate(xt, gt);
        *(v4f*)&ring[0][wv][q][gt][n16][0] = g0;
    }
    barrier_lds_only();  // hs zero-init + ring[0] visible

    for (int g = 0; g < TT / 4; g += 2) {
        set_gld(4 * g + 8);
        run_group(0, xA, xB);   // even group: reads ring[0], writes ring[1]
        set_gld(4 * g + 12);
        run_group(1, xB, xA);   // odd group
    }

    if constexpr (WRITE_LAST) {
        if (q < R) out_last[(size_t)(b0 + q) * 64 + j] = hcur;
    }
}

// ---------------- weight fp32 -> packed fp16 rows of 192 ----------------
__global__ __launch_bounds__(256)
void cvt_w(const float* __restrict__ w_ih, const float* __restrict__ w_hh,
           half_t* __restrict__ w16)
{
    const int id = blockIdx.x * 256 + threadIdx.x;  // 1024 rows * 192
    const int row = id / 192, k = id % 192;
    const float v = (k < 128) ? w_ih[row * 128 + k] : w_hh[row * 64 + (k - 128)];
    w16[id] = (half_t)v;
}

// ---------------- x fp32 -> fp16 ----------------
__global__ __launch_bounds__(256)
void cvt_x(const float* __restrict__ in, half_t* __restrict__ out)
{
    const size_t i = ((size_t)blockIdx.x * 256 + threadIdx.x) * 8;
    const float4 a = *(const float4*)(in + i);
    const float4 b = *(const float4*)(in + i + 4);
    v8h f;
    f[0] = (half_t)a.x; f[1] = (half_t)a.y; f[2] = (half_t)a.z; f[3] = (half_t)a.w;
    f[4] = (half_t)b.x; f[5] = (half_t)b.y; f[6] = (half_t)b.z; f[7] = (half_t)b.w;
    *(v8h*)(out + i) = f;
}

// ---------------- Layer 2 backward (single step, h0=0) + FC ----------------
__global__ __launch_bounds__(256)
void l2bwd_fc(const half_t* __restrict__ in, const float* __restrict__ w_ih,
              const float* __restrict__ b_ih, const float* __restrict__ b_hh,
              const float* __restrict__ hlast, const float* __restrict__ fc_w,
              const float* __restrict__ fc_b, float* __restrict__ out)
{
    const int b = blockIdx.x;
    const int g = threadIdx.x;
    __shared__ float gpre[256];
    __shared__ float hb[64];

    float acc = b_ih[3 * 256 + g] + b_hh[3 * 256 + g];
    const float* wp = w_ih + ((size_t)(3 * 256 + g)) * 128;
    const half_t* xp = in + ((size_t)b * TT + (TT - 1)) * 128;
    #pragma unroll
    for (int k = 0; k < 128; k += 8) {
        const float4 w0 = *(const float4*)(wp + k);
        const float4 w1 = *(const float4*)(wp + k + 4);
        const v8h xv = *(const v8h*)(xp + k);
        acc = fmaf(w0.x, (float)xv[0], acc); acc = fmaf(w0.y, (float)xv[1], acc);
        acc = fmaf(w0.z, (float)xv[2], acc); acc = fmaf(w0.w, (float)xv[3], acc);
        acc = fmaf(w1.x, (float)xv[4], acc); acc = fmaf(w1.y, (float)xv[5], acc);
        acc = fmaf(w1.z, (float)xv[6], acc); acc = fmaf(w1.w, (float)xv[7], acc);
    }
    gpre[g] = acc;
    __syncthreads();

    if (g < 64) {
        const float i  = sigf(gpre[g]);
        const float gg = tanhfast(gpre[128 + g]);
        const float o  = sigf(gpre[192 + g]);
        hb[g] = o * tanhfast(i * gg);
    }
    __syncthreads();

    if (g < 64) {
        float p = fc_w[g] * hlast[(size_t)b * 64 + g] + fc_w[64 + g] * hb[g];
        #pragma unroll
        for (int off = 32; off > 0; off >>= 1) p += __shfl_down(p, off);
        if (g == 0) out[b] = p + fc_b[0];
    }
}

extern "C" void kernel_launch(void* const* d_in, const int* in_sizes, int n_in,
                              void* d_out, int out_size, void* d_ws, size_t ws_size,
                              hipStream_t stream)
{
    const float* x    = (const float*)d_in[0];
    const float* w_ih = (const float*)d_in[1];
    const float* w_hh = (const float*)d_in[2];
    const float* b_ih = (const float*)d_in[3];
    const float* b_hh = (const float*)d_in[4];
    const float* fc_w = (const float*)d_in[5];
    const float* fc_b = (const float*)d_in[6];
    float* out = (float*)d_out;

    const size_t seq_b   = (size_t)BB * TT * 128 * sizeof(half_t);  // 128 MiB
    const size_t w16_b   = (size_t)1024 * 192 * sizeof(half_t);     // 384 KiB
    const size_t hlast_b = (size_t)BB * 64 * sizeof(float);         // 128 KiB

    if (ws_size >= w16_b + hlast_b + 2 * seq_b) {
        half_t* w16   = (half_t*)d_ws;
        float*  hlast = (float*)((char*)d_ws + w16_b);
        half_t* x16   = (half_t*)((char*)d_ws + w16_b + hlast_b);
        half_t* out1  = (half_t*)((char*)d_ws + w16_b + hlast_b + seq_b);

        cvt_w<<<768, 256, 0, stream>>>(w_ih, w_hh, w16);
        cvt_x<<<(BB * TT * 128 / 8) / 256, 256, 0, stream>>>(x, x16);
        lstm_scan<4, false, true, true, false><<<dim3(BB / 4, 2), 256, 0, stream>>>(
            x16, w16, w_ih, w_hh, b_ih, b_hh, 0, 1, out1, nullptr);
        lstm_scan<4, false, true, false, true><<<dim3(BB / 4, 1), 256, 0, stream>>>(
            out1, w16, w_ih, w_hh, b_ih, b_hh, 1, 0, nullptr, hlast);
        l2bwd_fc<<<BB, 256, 0, stream>>>(out1, w_ih, b_ih, b_hh, hlast, fc_w, fc_b, out);
    } else if (ws_size >= 2 * seq_b + hlast_b) {
        half_t* x16   = (half_t*)d_ws;
        half_t* out1  = (half_t*)((char*)d_ws + seq_b);
        float*  hlast = (float*)((char*)d_ws + 2 * seq_b);

        cvt_x<<<(BB * TT * 128 / 8) / 256, 256, 0, stream>>>(x, x16);
        lstm_scan<4, false, false, true, false><<<dim3(BB / 4, 2), 256, 0, stream>>>(
            x16, nullptr, w_ih, w_hh, b_ih, b_hh, 0, 1, out1, nullptr);
        lstm_scan<4, false, false, false, true><<<dim3(BB / 4, 1), 256, 0, stream>>>(
            out1, nullptr, w_ih, w_hh, b_ih, b_hh, 1, 0, nullptr, hlast);
        l2bwd_fc<<<BB, 256, 0, stream>>>(out1, w_ih, b_ih, b_hh, hlast, fc_w, fc_b, out);
    } else {
        half_t* out1  = (half_t*)d_ws;
        float*  hlast = (float*)((char*)d_ws + seq_b);

        lstm_scan<4, true, false, true, false><<<dim3(BB / 4, 2), 256, 0, stream>>>(
            x, nullptr, w_ih, w_hh, b_ih, b_hh, 0, 1, out1, nullptr);
        lstm_scan<4, false, false, false, true><<<dim3(BB / 4, 1), 256, 0, stream>>>(
            out1, nullptr, w_ih, w_hh, b_ih, b_hh, 1, 0, nullptr, hlast);
        l2bwd_fc<<<BB, 256, 0, stream>>>(out1, w_ih, b_ih, b_hh, hlast, fc_w, fc_b, out);
    }
}